// Round 1
// 761.925 us; speedup vs baseline: 1.1094x; 1.1094x over previous
//
#include <hip/hip_runtime.h>
#include <math.h>

#define B_ 32
#define L_ 4096
#define D_ 1024
#define A_ 8
#define CHUNK 256
#define NCH (L_ / CHUNK)   // 16 chunks per batch row
#define NSB 7

// ---------------------------------------------------------------------------
// Kernel 1: masked segmented sum of embeddings into per-(b,chunk,action)
// PARTIAL buckets. grid = B * NCH blocks, 256 threads. Thread t owns dims
// [4t, 4t+3]. Action index per position is block-uniform -> readfirstlane +
// scalar switch. No atomics, no workspace zero-init: every partial slot is
// written unconditionally (poison-safe).
// NOTE: mask arrives as int32 (harness promotes bool -> int32).
// ---------------------------------------------------------------------------
__global__ __launch_bounds__(256) void k_accum(
    const float* __restrict__ emb, const int* __restrict__ actions,
    const int* __restrict__ mask,
    float* __restrict__ psums /*B*A*NCH*D*/,
    float* __restrict__ pcnt  /*B*A*NCH*/)
{
  const int b  = blockIdx.x / NCH;
  const int c  = blockIdx.x % NCH;
  const int l0 = c * CHUNK;
  const int t  = threadIdx.x;

  __shared__ int s_act[CHUNK];
  for (int i = t; i < CHUNK; i += 256) {
    const int idx = b * L_ + l0 + i;
    const int a = actions[idx];
    s_act[i] = (mask[idx] != 0) ? a : -1;
  }
  __syncthreads();

  // per-block action counts (threads 0..7); overlaps with main loop below
  if (t < A_) {
    int cnt = 0;
    for (int i = 0; i < CHUNK; ++i) cnt += (s_act[i] == t) ? 1 : 0;
    pcnt[(b * A_ + t) * NCH + c] = (float)cnt;
  }

  float4 acc[A_];
#pragma unroll
  for (int j = 0; j < A_; ++j) acc[j] = make_float4(0.f, 0.f, 0.f, 0.f);

  const float4* __restrict__ row =
      (const float4*)(emb + (size_t)(b * L_ + l0) * D_);

#define ADD4(J, V) \
  acc[J].x += (V).x; acc[J].y += (V).y; acc[J].z += (V).z; acc[J].w += (V).w

#pragma unroll 1
  for (int i = 0; i < CHUNK; i += 8) {
    float4 v[8];
#pragma unroll
    for (int u = 0; u < 8; ++u) v[u] = row[(size_t)(i + u) * (D_ / 4) + t];
#pragma unroll
    for (int u = 0; u < 8; ++u) {
      const int a = __builtin_amdgcn_readfirstlane(s_act[i + u]);
      switch (a) {
        case 0: ADD4(0, v[u]); break;
        case 1: ADD4(1, v[u]); break;
        case 2: ADD4(2, v[u]); break;
        case 3: ADD4(3, v[u]); break;
        case 4: ADD4(4, v[u]); break;
        case 5: ADD4(5, v[u]); break;
        case 6: ADD4(6, v[u]); break;
        case 7: ADD4(7, v[u]); break;
        default: break;
      }
    }
  }
#undef ADD4

  // coalesced partial stores: one float4 per (action); 8 x 4KB per block
#pragma unroll
  for (int j = 0; j < A_; ++j) {
    float4* p =
        (float4*)(psums + ((size_t)(b * A_ + j) * NCH + c) * D_) + t;
    *p = acc[j];
  }
}

// ---------------------------------------------------------------------------
// Kernel 2: reduce partials -> feats; two tiny MLP heads + epilogues.
// grid = B*A blocks (one (b,a) row each), 256 threads.
// Layer-1 matvecs use ALL 256 threads: 2 threads/col (shift, 128 cols) and
// 4 threads/col (effects, 64 cols) with LDS combine -> half the serial depth
// and 2x the loads in flight vs one-thread-per-column.
// ---------------------------------------------------------------------------
__global__ __launch_bounds__(256) void k_head(
    const float* __restrict__ psums, const float* __restrict__ pcnt,
    const float* __restrict__ sw1, const float* __restrict__ sb1,
    const float* __restrict__ sw2, const float* __restrict__ sb2,
    const float* __restrict__ ew1, const float* __restrict__ eb1,
    const float* __restrict__ ew2, const float* __restrict__ eb2,
    float* __restrict__ out)
{
  const int ba = blockIdx.x;   // b*A + a
  const int t  = threadIdx.x;

  __shared__ float s_feat[D_];
  __shared__ float s_pA[256];
  __shared__ float s_pB[256];
  __shared__ float s_h1[128];
  __shared__ float s_he[64];
  __shared__ float s_logits[2 * NSB];
  __shared__ float s_eff[3];
  __shared__ float s_cnt16[NCH];

  if (t < NCH) s_cnt16[t] = pcnt[ba * NCH + t];

  // reduce 16 chunk-partials; thread t owns dims [4t, 4t+3]
  float4 a = make_float4(0.f, 0.f, 0.f, 0.f);
  const float4* __restrict__ ps =
      (const float4*)(psums + (size_t)ba * NCH * D_);
#pragma unroll
  for (int c = 0; c < NCH; ++c) {
    const float4 v = ps[(size_t)c * (D_ / 4) + t];
    a.x += v.x; a.y += v.y; a.z += v.z; a.w += v.w;
  }
  __syncthreads();   // s_cnt16 visible

  float cnt = 0.f;
#pragma unroll
  for (int i = 0; i < NCH; ++i) cnt += s_cnt16[i];
  const float inv = 1.0f / fmaxf(cnt, 1.0f);

  a.x *= inv; a.y *= inv; a.z *= inv; a.w *= inv;
  ((float4*)s_feat)[t] = a;
  __syncthreads();

  // phase A: shift layer1 (128 cols), 2 threads per column over half of D
  {
    const int col = t & 127;
    const int d0  = (t >> 7) * (D_ / 2);
    float acc = 0.f;
#pragma unroll 8
    for (int d = 0; d < D_ / 2; ++d)
      acc += s_feat[d0 + d] * sw1[(d0 + d) * 128 + col];
    s_pA[t] = acc;
  }
  // phase B: effects layer1 (64 cols), 4 threads per column over quarter of D
  {
    const int col = t & 63;
    const int d0  = (t >> 6) * (D_ / 4);
    float acc = 0.f;
#pragma unroll 8
    for (int d = 0; d < D_ / 4; ++d)
      acc += s_feat[d0 + d] * ew1[(d0 + d) * 64 + col];
    s_pB[t] = acc;
  }
  __syncthreads();

  if (t < 128) {
    s_h1[t] = fmaxf(s_pA[t] + s_pA[128 + t] + sb1[t], 0.f);
  } else if (t < 192) {
    const int j = t - 128;
    s_he[j] = fmaxf(s_pB[j] + s_pB[64 + j] + s_pB[128 + j] + s_pB[192 + j]
                    + eb1[j], 0.f);
  }
  __syncthreads();

  if (t < 2 * NSB) {
    float acc = sb2[t];
#pragma unroll 4
    for (int k = 0; k < 128; ++k) acc += s_h1[k] * sw2[k * (2 * NSB) + t];
    s_logits[t] = acc;
  } else if (t < 2 * NSB + 3) {
    const int j = t - 2 * NSB;
    float acc = eb2[j];
#pragma unroll 4
    for (int k = 0; k < 64; ++k) acc += s_he[k] * ew2[k * 3 + j];
    s_eff[j] = acc;
  }
  __syncthreads();

  const float seen = (cnt > 0.f) ? 1.f : 0.f;

  float* __restrict__ out0 = out;                 // (B,A,2)   512
  float* __restrict__ out1 = out + 512;           // (B,A,7)  1792
  float* __restrict__ out2 = out + 2304;          // (B,A,7)  1792
  float* __restrict__ out3 = out + 4096;          // (B,A)     256
  float* __restrict__ out4 = out + 4352;          // (B,A)     256
  float* __restrict__ out5 = out + 4608;          // (B,A)     256

  if (t < NSB) {
    out1[ba * NSB + t] = s_logits[t];
    out2[ba * NSB + t] = s_logits[NSB + t];
  }

  if (t == 0) {
    const float bins[NSB] = {-16.f, -8.f, -4.f, 0.f, 4.f, 8.f, 16.f};
    float dxy[2];
#pragma unroll
    for (int h = 0; h < 2; ++h) {
      const float* lg = &s_logits[h * NSB];
      float m = lg[0];
      for (int i = 1; i < NSB; ++i) m = fmaxf(m, lg[i]);
      float s = 0.f, acc = 0.f;
      for (int i = 0; i < NSB; ++i) {
        const float e = expf(lg[i] - m);
        s += e;
        acc += e * bins[i];
      }
      dxy[h] = acc / s;
    }
    out0[ba * 2 + 0] = dxy[0] * seen;
    out0[ba * 2 + 1] = dxy[1] * seen;
    out3[ba] = (1.f / (1.f + expf(-s_eff[0]))) * seen;
    out4[ba] = (1.f / (1.f + expf(-s_eff[1]))) * seen;
    out5[ba] = s_eff[2] * seen;
  }
}

extern "C" void kernel_launch(void* const* d_in, const int* in_sizes, int n_in,
                              void* d_out, int out_size, void* d_ws, size_t ws_size,
                              hipStream_t stream) {
  const float* emb     = (const float*)d_in[0];
  const int*   actions = (const int*)d_in[1];
  const int*   mask    = (const int*)d_in[2];
  const float* sw1 = (const float*)d_in[3];
  const float* sb1 = (const float*)d_in[4];
  const float* sw2 = (const float*)d_in[5];
  const float* sb2 = (const float*)d_in[6];
  const float* ew1 = (const float*)d_in[7];
  const float* eb1 = (const float*)d_in[8];
  const float* ew2 = (const float*)d_in[9];
  const float* eb2 = (const float*)d_in[10];
  float* out = (float*)d_out;

  // Workspace: partial sums [B][A][NCH][D] = 16.8 MB, partial counts = 16 KB.
  // Every slot is written unconditionally by k_accum -> no zero-init needed,
  // no memset dispatch.
  float* psums = (float*)d_ws;
  float* pcnt  = psums + (size_t)B_ * A_ * NCH * D_;

  hipLaunchKernelGGL(k_accum, dim3(B_ * NCH), dim3(256), 0, stream,
                     emb, actions, mask, psums, pcnt);
  hipLaunchKernelGGL(k_head, dim3(B_ * A_), dim3(256), 0, stream,
                     psums, pcnt, sw1, sb1, sw2, sb2, ew1, eb1, ew2, eb2, out);
}